// Round 13
// baseline (386.447 us; speedup 1.0000x reference)
//
#include <hip/hip_runtime.h>
#include <cstdint>

// Problem constants
#define TT 512   // KVLEN
#define CC 512   // C
#define HH 8     // heads
#define NN 64    // head dim
#define BQ 32    // BATCH*QLEN
#define NB 4     // BATCH
#define TG 128   // TT/4 packed groups

__device__ __forceinline__ float sigm(float x){ return 1.f/(1.f+__expf(-x)); }

__device__ __forceinline__ float wsum(float x){
  #pragma unroll
  for (int o=32;o;o>>=1) x += __shfl_xor(x, o, 64);
  return x;
}

// ---------------------------------------------------------------------------
// Batched wave64 row-sum, VALU-only: DPP row_ror tree + permlane16/32 swap.
// ---------------------------------------------------------------------------
template<int NR>
__device__ __forceinline__ void rowsum64_batch(float* x){
  #pragma unroll
  for (int i=0;i<NR;i++)
    x[i] += __int_as_float(__builtin_amdgcn_mov_dpp(__float_as_int(x[i]), 0x121, 0xf, 0xf, true));
  #pragma unroll
  for (int i=0;i<NR;i++)
    x[i] += __int_as_float(__builtin_amdgcn_mov_dpp(__float_as_int(x[i]), 0x122, 0xf, 0xf, true));
  #pragma unroll
  for (int i=0;i<NR;i++)
    x[i] += __int_as_float(__builtin_amdgcn_mov_dpp(__float_as_int(x[i]), 0x124, 0xf, 0xf, true));
  #pragma unroll
  for (int i=0;i<NR;i++)
    x[i] += __int_as_float(__builtin_amdgcn_mov_dpp(__float_as_int(x[i]), 0x128, 0xf, 0xf, true));
  float y[NR];
  #pragma unroll
  for (int i=0;i<NR;i++) asm("v_mov_b32 %0, %1" : "=v"(y[i]) : "v"(x[i]));
  #pragma unroll
  for (int i=0;i<NR;i++) asm("v_permlane16_swap_b32 %0, %1" : "+v"(x[i]), "+v"(y[i]));
  #pragma unroll
  for (int i=0;i<NR;i++) x[i] += y[i];
  #pragma unroll
  for (int i=0;i<NR;i++) asm("v_mov_b32 %0, %1" : "=v"(y[i]) : "v"(x[i]));
  #pragma unroll
  for (int i=0;i<NR;i++) asm("v_permlane32_swap_b32 %0, %1" : "+v"(x[i]), "+v"(y[i]));
  #pragma unroll
  for (int i=0;i<NR;i++) x[i] += y[i];
}

// ---------------------------------------------------------------------------
// k_ps: FUSED k_prep + k_shift (R13).  Independent sub-kernels, one launch.
// Blocks 0..31: prep (per-bq small dots -> Qw/Qa/ghw/xrw) — first, since
// its consumer chain (k_rg) is longest.  Blocks 32..1055: token-shift mix.
// ---------------------------------------------------------------------------
__global__ __launch_bounds__(256) void k_ps(
  const float* __restrict__ q, const float* __restrict__ kv,
  const float* __restrict__ x_r, const float* __restrict__ x_w,
  const float* __restrict__ x_a, const float* __restrict__ x_g,
  const float* __restrict__ w1, const float* __restrict__ a1,
  const float* __restrict__ g1,
  float* __restrict__ Qw, float* __restrict__ Qa,
  float* __restrict__ ghw, float* __restrict__ xrw,
  const float* __restrict__ x_k, const float* __restrict__ x_v,
  float* __restrict__ xk, float* __restrict__ xv)
{
  int bid = blockIdx.x;
  int tid = threadIdx.x;
  if (bid < 32){
    // ----- prep part -----
    int bq = bid, b = bq >> 3;
    int wave = tid >> 6, lane = tid & 63;
    __shared__ float qxw[CC], qxa[CC], sxg[CC];
    for (int c = tid; c < CC; c += 256){
      float qv = q[bq*CC + c];
      float kl = kv[((size_t)b*TT + (TT-1))*CC + c];
      xrw[bq*CC + c] = kl + (qv - kl)*x_r[c];
      sxg[c] = kl + (qv - kl)*x_g[c];
      qxw[c] = qv*x_w[c];
      qxa[c] = qv*x_a[c];
    }
    __syncthreads();
    for (int dot = wave; dot < 160; dot += 4){
      const float* buf; const float* W; int ld, dd;
      if (dot < 32)      { buf = qxw; W = w1; ld = 32; dd = dot; }
      else if (dot < 64) { buf = qxa; W = a1; ld = 32; dd = dot-32; }
      else               { buf = sxg; W = g1; ld = 96; dd = dot-64; }
      float s = 0.f;
      #pragma unroll
      for (int m = 0; m < 8; m++){
        int c = m*64 + lane;
        s = fmaf(buf[c], W[c*ld + dd], s);
      }
      s = wsum(s);
      if (lane == 0){
        if (dot < 32)      Qw[bq*32 + dd] = s;
        else if (dot < 64) Qa[bq*32 + dd] = s;
        else               ghw[bq*96 + dd] = sigm(s);
      }
    }
  } else {
    // ----- shift part -----
    int g = (bid - 32)*256 + tid;              // float4 index, [0, 262144)
    int bt = g >> 7, t = bt & (TT-1), c4 = g & 127;
    const float4* kv4 = (const float4*)kv;
    float4 cur = kv4[g];
    float4 sh  = t ? kv4[g-128] : make_float4(0.f,0.f,0.f,0.f);
    float4 kc  = ((const float4*)x_k)[c4];
    float4 vc  = ((const float4*)x_v)[c4];
    float4 ok, ov;
    ok.x = cur.x + (sh.x-cur.x)*kc.x; ov.x = cur.x + (sh.x-cur.x)*vc.x;
    ok.y = cur.y + (sh.y-cur.y)*kc.y; ov.y = cur.y + (sh.y-cur.y)*vc.y;
    ok.z = cur.z + (sh.z-cur.z)*kc.z; ov.z = cur.z + (sh.z-cur.z)*vc.z;
    ok.w = cur.w + (sh.w-cur.w)*kc.w; ov.w = cur.w + (sh.w-cur.w)*vc.w;
    ((float4*)xk)[g] = ok;
    ((float4*)xv)[g] = ov;
  }
}

// ---------------------------------------------------------------------------
// k_rgmm: FUSED k_rg + gemm2 + k_pgemm (R13).  One 864-block dispatch.
// Blocks 0..95: pgemm (latency-bound, starts earliest).
// Blocks 96..351: k_rg (rrow/grow per-bq rows).
// Blocks 352..863: two [2048x512]@[512x512] packed-store GEMMs.
// ---------------------------------------------------------------------------
__global__ __launch_bounds__(256) void k_rgmm(
  const float* __restrict__ xrw, const float* __restrict__ ghw,
  const float* __restrict__ Wr, const float* __restrict__ g2,
  float* __restrict__ rrow, float* __restrict__ grow,
  const float* __restrict__ xk, const float* __restrict__ Wk,
  float* __restrict__ kgP,
  const float* __restrict__ xv, const float* __restrict__ Wv,
  float* __restrict__ vpP,
  const float* __restrict__ kv,
  const float* __restrict__ x_w, const float* __restrict__ x_a,
  const float* __restrict__ w1, const float* __restrict__ a1,
  const float* __restrict__ v1,
  float* __restrict__ Pw, float* __restrict__ Pa, float* __restrict__ HV)
{
  int bid = blockIdx.x;
  int tid = threadIdx.x;

  if (bid < 96){
    // ----- pgemm part -----
    __shared__ float As[32][65];
    __shared__ float Bs[32][32];
    __shared__ float scl[CC];
    int mat = bid / 32;
    int r0 = (bid % 32) * 64;
    const float* A = (mat == 2) ? xv : kv;
    const float* B = (mat == 0) ? w1 : (mat == 1) ? a1 : v1;
    float* O       = (mat == 0) ? Pw : (mat == 1) ? Pa : HV;
    for (int c = tid; c < CC; c += 256)
      scl[c] = (mat == 0) ? (1.f - x_w[c]) : (mat == 1) ? (1.f - x_a[c]) : 1.f;
    __syncthreads();
    int tx = tid & 31, ty = tid >> 5;
    float acc[8];
    #pragma unroll
    for (int i = 0; i < 8; i++) acc[i] = 0.f;
    for (int k0 = 0; k0 < 512; k0 += 32){
      #pragma unroll
      for (int p = 0; p < 8; p++){
        int e = tid + p*256;
        int kk2 = e & 31, r = e >> 5;
        As[kk2][r] = A[(size_t)(r0+r)*512 + k0 + kk2] * scl[k0 + kk2];
      }
      #pragma unroll
      for (int p = 0; p < 4; p++){
        int e = tid + p*256;
        int n = e & 31, kk2 = e >> 5;
        Bs[kk2][n] = B[(size_t)(k0+kk2)*32 + n];
      }
      __syncthreads();
      #pragma unroll
      for (int kk2 = 0; kk2 < 32; kk2++){
        float bb = Bs[kk2][tx];
        #pragma unroll
        for (int i = 0; i < 8; i++)
          acc[i] = fmaf(As[kk2][ty*8 + i], bb, acc[i]);
      }
      __syncthreads();
    }
    #pragma unroll
    for (int i = 0; i < 8; i++)
      O[(size_t)(r0 + ty*8 + i)*32 + tx] = acc[i];
  } else if (bid < 352){
    // ----- k_rg part -----
    int idx = bid - 96;
    int bq = idx >> 3; int co0 = (idx & 7)*64;
    int tx = tid & 63, ty = tid >> 6;
    __shared__ float sxr[CC];
    __shared__ float sgh[96];
    __shared__ float red[4][64];
    sxr[tid]     = xrw[bq*CC + tid];
    sxr[tid+256] = xrw[bq*CC + tid + 256];
    if (tid < 96) sgh[tid] = ghw[bq*96 + tid];
    __syncthreads();
    float p = 0.f;
    for (int i = 0; i < 128; i++){
      int c = ty*128 + i;
      p = fmaf(sxr[c], Wr[(size_t)c*CC + co0 + tx], p);
    }
    red[ty][tx] = p;
    float pg = 0.f;
    for (int d = ty*24; d < ty*24 + 24; d++)
      pg = fmaf(sgh[d], g2[(size_t)d*CC + co0 + tx], pg);
    __syncthreads();
    if (ty == 0)
      rrow[bq*CC + co0 + tx] = (red[0][tx]+red[1][tx])+(red[2][tx]+red[3][tx]);
    __syncthreads();
    red[ty][tx] = pg;
    __syncthreads();
    if (ty == 0)
      grow[bq*CC + co0 + tx] = (red[0][tx]+red[1][tx])+(red[2][tx]+red[3][tx]);
  } else {
    // ----- gemm part -----
    __shared__ float As[32][68];
    __shared__ float Bs[32][64];
    int gb = bid - 352;
    int z = gb >> 8; int tile = gb & 255;
    const float* A = z ? xv : xk;
    const float* W = z ? Wv : Wk;
    int tx = tid & 15, ty = tid >> 4;
    int m0 = (tile >> 3)*64, n0 = (tile & 7)*64;
    float acc[4][4];
    #pragma unroll
    for (int i=0;i<4;i++)
      #pragma unroll
      for (int j=0;j<4;j++) acc[i][j]=0.f;

    for (int k0 = 0; k0 < 512; k0 += 32){
      #pragma unroll
      for (int i = 0; i < 8; i++){
        int e = tid + i*256;
        int kk = e & 31, m = e >> 5;
        As[kk][m] = A[(size_t)(m0+m)*512 + k0 + kk];
      }
      #pragma unroll
      for (int i = 0; i < 8; i++){
        int e = tid + i*256;
        int n = e & 63, kk = e >> 6;
        Bs[kk][n] = W[(size_t)(k0+kk)*512 + n0 + n];
      }
      __syncthreads();
      #pragma unroll
      for (int kk = 0; kk < 32; kk++){
        float a4[4], b4[4];
        #pragma unroll
        for (int i=0;i<4;i++) a4[i] = As[kk][ty*4+i];
        #pragma unroll
        for (int j=0;j<4;j++) b4[j] = Bs[kk][tx*4+j];
        #pragma unroll
        for (int i=0;i<4;i++)
          #pragma unroll
          for (int j=0;j<4;j++) acc[i][j] += a4[i]*b4[j];
      }
      __syncthreads();
    }
    // packed store: rows m..m+3 are 4 consecutive t (u=0..3)
    int m = m0 + ty*4;
    int b = m >> 9, t = m & (TT-1), tg = t >> 2;
    int h = n0 >> 6;
    float* dstB = z ? vpP : kgP;
    float4* dst = (float4*)dstB + ((size_t)(b*HH + h)*TG + tg)*64 + tx*4;
    #pragma unroll
    for (int j=0;j<4;j++)
      dst[j] = make_float4(acc[0][j],acc[1][j],acc[2][j],acc[3][j]);
  }
}

// ---------------------------------------------------------------------------
// k_swa: FUSED k_svn + k_wa (R12); both 512-thr, mutually independent.
// Blocks 0..511: svn (kk-normalize + sv, packed).
// Blocks 512..4607: wa (decay w + a_sig, packed).
// ---------------------------------------------------------------------------
__global__ __launch_bounds__(512) void k_swa(
  const float* __restrict__ HV, const float* __restrict__ v2,
  const float* __restrict__ v0, const float* __restrict__ k_k,
  const float* __restrict__ kgP,
  float* __restrict__ svP, float* __restrict__ kkP,
  const float* __restrict__ Pw, const float* __restrict__ Pa,
  const float* __restrict__ Qw, const float* __restrict__ Qa,
  const float* __restrict__ w2, const float* __restrict__ a2,
  const float* __restrict__ w0, const float* __restrict__ a0,
  float* __restrict__ wP, float* __restrict__ aP)
{
  int bid = blockIdx.x;
  int tid = threadIdx.x;
  if (bid < NB*TG){
    // ----- svn part -----
    int b = bid >> 7, tg = bid & (TG-1);
    __shared__ float hv[4][32];
    if (tid < 128){
      int u = tid >> 5, d = tid & 31;
      hv[u][d] = HV[((size_t)(b*TT + tg*4 + u))*32 + d];
    }
    __syncthreads();
    int c = tid, h = c >> 6, cc0 = c & 63;
    size_t o = ((size_t)(b*HH + h)*TG + tg)*64 + cc0;
    float4 kg4 = ((const float4*)kgP)[o];
    float kkc = k_k[c];
    float q0 = kg4.x*kkc, q1 = kg4.y*kkc, q2 = kg4.z*kkc, q3 = kg4.w*kkc;
    float ss[4] = {q0*q0, q1*q1, q2*q2, q3*q3};
    rowsum64_batch<4>(ss);            // per-wave = per-head sum
    float4 kkq;
    kkq.x = q0 / fmaxf(sqrtf(ss[0]), 1e-12f);
    kkq.y = q1 / fmaxf(sqrtf(ss[1]), 1e-12f);
    kkq.z = q2 / fmaxf(sqrtf(ss[2]), 1e-12f);
    kkq.w = q3 / fmaxf(sqrtf(ss[3]), 1e-12f);
    ((float4*)kkP)[o] = kkq;
    float v0c = v0[c];
    float s0 = v0c, s1 = v0c, s2 = v0c, s3 = v0c;
    #pragma unroll
    for (int d = 0; d < 32; d++){
      float vc = v2[d*CC + c];
      s0 = fmaf(hv[0][d], vc, s0);
      s1 = fmaf(hv[1][d], vc, s1);
      s2 = fmaf(hv[2][d], vc, s2);
      s3 = fmaf(hv[3][d], vc, s3);
    }
    ((float4*)svP)[o] = make_float4(sigm(s0), sigm(s1), sigm(s2), sigm(s3));
  } else {
    // ----- wa part -----
    int blk = bid - NB*TG;             // bq*TG + tg
    int bq = blk >> 7, tg = blk & (TG-1), t0 = tg*4, b = bq >> 3;
    __shared__ float sth[4][32], sal[4][32];
    if (tid < 256){
      int g = (tid >> 5) & 3, d = tid & 31;
      int pidx = ((b << 9) | (t0 + g))*32 + d;
      if (tid < 128) sth[g][d] = tanhf(Pw[pidx] + Qw[bq*32 + d]);
      else           sal[g][d] = Pa[pidx] + Qa[bq*32 + d];
    }
    __syncthreads();
    int c = tid, h = c >> 6, cc0 = c & 63;
    float wreg[32], areg[32];
    #pragma unroll
    for (int d = 0; d < 32; d++){ wreg[d] = w2[d*CC + c]; areg[d] = a2[d*CC + c]; }
    float w0c = w0[c], a0c = a0[c];
    float w4a[4], a4a[4];
    #pragma unroll
    for (int g = 0; g < 4; g++){
      float wa = 0.f, aa = 0.f;
      #pragma unroll
      for (int d = 0; d < 32; d++){
        wa = fmaf(sth[g][d], wreg[d], wa);
        aa = fmaf(sal[g][d], areg[d], aa);
      }
      w4a[g] = __expf(-0.60653066f * sigm(w0c + wa));
      a4a[g] = sigm(a0c + aa);
    }
    size_t o = ((size_t)(bq*HH + h)*TG + tg)*64 + cc0;
    ((float4*)wP)[o] = make_float4(w4a[0],w4a[1],w4a[2],w4a[3]);
    ((float4*)aP)[o] = make_float4(a4a[0],a4a[1],a4a[2],a4a[3]);
  }
}

// ---------------------------------------------------------------------------
// K3: BACKWARD vector scan — R11 structure (~63-71us measured): R5 geometry,
// vf-passthrough stores youngest per iteration, k/b in-flight.
//   out += v_s (k_s . g_s);  g_{s-1} = w_s*g_s - kk_s (b_s . g_s)
//   k = kg*(1+(a-1)k_a),  b = kk*a.
// ---------------------------------------------------------------------------
#define SCAN_STEP(wc,ac,gc,nc,pc,sc,vfc) do{ \
  float vj = fmaf((vfc)-(pc), (sc), (pc)); \
  float kc = (gc)*fmaf((ac)-1.f, kac, 1.f); \
  float bc = (nc)*(ac); \
  float rr[2]; rr[0]=kc*g; rr[1]=bc*g; \
  rowsum64_batch<2>(rr); \
  out = fmaf(rr[0], vj, out); \
  g = fmaf((wc), g, -((nc)*rr[1])); }while(0)

__global__ __launch_bounds__(64, 1) void k_scan(
  const float* __restrict__ wP, const float* __restrict__ aP,
  const float* __restrict__ kgP, const float* __restrict__ kkP,
  const float* __restrict__ vpP, const float* __restrict__ svP,
  const float* __restrict__ vfirst,
  const float* __restrict__ rrow, const float* __restrict__ grow,
  const float* __restrict__ r_k, const float* __restrict__ k_a,
  const float* __restrict__ ln_w, const float* __restrict__ ln_b,
  float* __restrict__ xo, float* __restrict__ vf_out)
{
  int blk = blockIdx.x; int bq = blk >> 3, h = blk & 7, b = bq >> 3;
  int lane = threadIdx.x & 63;

  // per-(bq,h)/(b,h) packed bases: TG*64 float4s each
  const float4* wp4 = (const float4*)wP  + ((size_t)(bq*HH + h))*TG*64 + lane;
  const float4* ap4 = (const float4*)aP  + ((size_t)(bq*HH + h))*TG*64 + lane;
  const float4* gp4 = (const float4*)kgP + ((size_t)(b*HH + h))*TG*64 + lane;
  const float4* np4 = (const float4*)kkP + ((size_t)(b*HH + h))*TG*64 + lane;
  const float4* pp4 = (const float4*)vpP + ((size_t)(b*HH + h))*TG*64 + lane;
  const float4* sp4 = (const float4*)svP + ((size_t)(b*HH + h))*TG*64 + lane;
  const float*  pvf = vfirst + (size_t)bq*TT*CC + h*NN + lane;
  float*        pvo = vf_out + (size_t)bq*TT*CC + h*NN + lane;

  float kac = k_a[h*NN + lane];
  float g   = rrow[(size_t)bq*CC + h*NN + lane];   // g_{T-1} = r
  float out = 0.f;

  constexpr int PD = 4;                // prefetch depth, in groups of 4 steps
  float4 fw[PD], fa[PD], fg[PD], fn[PD], fp[PD], fs[PD];
  float fv0[PD], fv1[PD], fv2[PD], fv3[PD];
  #pragma unroll
  for (int d = 0; d < PD; ++d){
    int gg = TG-1 - d; int go = gg*64;
    fw[d]=wp4[go]; fa[d]=ap4[go]; fg[d]=gp4[go]; fn[d]=np4[go];
    fp[d]=pp4[go]; fs[d]=sp4[go];
    const float* pv = pvf + (size_t)(4*gg)*CC;
    fv0[d]=pv[0]; fv1[d]=pv[CC]; fv2[d]=pv[2*CC]; fv3[d]=pv[3*CC];
  }

  #pragma unroll 1
  for (int gb = 0; gb < TG; gb += PD){
    #pragma unroll
    for (int sl = 0; sl < PD; ++sl){
      int gi = TG-1 - (gb + sl);       // current group (descending)
      // snapshot slot
      float4 w4=fw[sl], a4=fa[sl], g4=fg[sl], n4=fn[sl], p4=fp[sl], s4=fs[sl];
      float v3=fv3[sl], v2_=fv2[sl], v1_=fv1[sl], v0_=fv0[sl];
      // prefetch group gi-PD into slot sl (clamped; dup loads harmless)
      int gp = gi - PD; gp = gp < 0 ? 0 : gp; int go = gp*64;
      fw[sl]=wp4[go]; fa[sl]=ap4[go]; fg[sl]=gp4[go]; fn[sl]=np4[go];
      fp[sl]=pp4[go]; fs[sl]=sp4[go];
      { const float* pv = pvf + (size_t)(4*gp)*CC;
        fv0[sl]=pv[0]; fv1[sl]=pv[CC]; fv2[sl]=pv[2*CC]; fv3[sl]=pv[3*CC]; }
      // v_first passthrough: issued AFTER the prefetch loads so the stores
      // are the youngest vmem ops — load-consume vmcnt waits no longer
      // require store retirement (R10 regression mechanism).
      {
        float* po = pvo + (size_t)(4*gi)*CC;
        po[0] = v0_; po[CC] = v1_; po[2*CC] = v2_; po[3*CC] = v3;
      }
      __builtin_amdgcn_sched_barrier(0);   // pin loads/stores in this iteration
      // 4 steps, s = 4*gi+3 .. 4*gi+0
      SCAN_STEP(w4.w,a4.w,g4.w,n4.w,p4.w,s4.w,v3);
      SCAN_STEP(w4.z,a4.z,g4.z,n4.z,p4.z,s4.z,v2_);
      SCAN_STEP(w4.y,a4.y,g4.y,n4.y,p4.y,s4.y,v1_);
      SCAN_STEP(w4.x,a4.x,g4.x,n4.x,p4.x,s4.x,v0_);
    }
  }

  // epilogue: groupnorm over head + rk*v term + gate (per-lane channel)
  {
    float mean = wsum(out) * (1.f/NN);
    float dv = out - mean;
    float var = wsum(dv*dv) * (1.f/NN);
    float yn = dv * rsqrtf(var + 6.4e-4f);   // GN_EPS = 1e-5*64
    int c = h*NN + lane;
    float y2 = yn * ln_w[c] + ln_b[c];
    int goT = (TG-1)*64;
    float kgT = gp4[goT].w, aT = ap4[goT].w;
    float kl  = kgT * fmaf(aT - 1.f, kac, 1.f);   // k_final at t = T-1
    float rl  = rrow[(size_t)bq*CC + c];
    float rk  = wsum(rl*kl*r_k[c]);
    float vp_ = pp4[goT].w, sv_ = sp4[goT].w;
    float vf_ = pvf[(size_t)(TT-1)*CC];
    float v_i = fmaf(vf_ - vp_, sv_, vp_);   // v_{T-1}
    float res = (y2 + rk*v_i) * grow[(size_t)bq*CC + c];
    xo[bq*CC + c] = res;
  }
}

// ---------------------------------------------------------------------------
// K4: out[bq,co] = xo[bq,:] @ Wo[:,co]
// ---------------------------------------------------------------------------
__global__ __launch_bounds__(256) void k_out(
  const float* __restrict__ xo, const float* __restrict__ Wo,
  float* __restrict__ outp)
{
  int bq = blockIdx.y; int co0 = blockIdx.x*64;
  int tid = threadIdx.x, tx = tid & 63, ty = tid >> 6;
  __shared__ float row[CC];
  __shared__ float red[4][64];
  row[tid]     = xo[bq*CC + tid];
  row[tid+256] = xo[bq*CC + tid + 256];
  __syncthreads();
  float p = 0.f;
  for (int i = 0; i < 128; i++){
    int c = ty*128 + i;
    p = fmaf(row[c], Wo[(size_t)c*CC + co0 + tx], p);
  }
  red[ty][tx] = p;
  __syncthreads();
  if (ty == 0)
    outp[bq*CC + co0 + tx] = (red[0][tx]+red[1][tx])+(red[2][tx]+red[3][tx]);
}

// ---------------------------------------------------------------------------
extern "C" void kernel_launch(void* const* d_in, const int* in_sizes, int n_in,
                              void* d_out, int out_size, void* d_ws, size_t ws_size,
                              hipStream_t stream)
{
  const float* q   = (const float*)d_in[0];
  const float* kv  = (const float*)d_in[1];
  const float* vf  = (const float*)d_in[2];
  const float* x_r = (const float*)d_in[3];
  const float* x_w = (const float*)d_in[4];
  const float* x_k = (const float*)d_in[5];
  const float* x_v = (const float*)d_in[6];
  const float* x_a = (const float*)d_in[7];
  const float* x_g = (const float*)d_in[8];
  const float* w0  = (const float*)d_in[9];
  const float* w1  = (const float*)d_in[10];
  const float* w2  = (const float*)d_in[11];
  const float* a0  = (const float*)d_in[12];
  const float* a1  = (const float*)d_in[13];
  const float* a2  = (const float*)d_in[14];
  const float* v0  = (const float*)d_in[15];
  const float* v1  = (const float*)d_in[16];
  const float* v2  = (const float*)d_in[17];
  const float* g1  = (const float*)d_in[18];
  const float* g2  = (const float*)d_in[19];
  const float* k_k = (const float*)d_in[20];
  const float* k_a = (const float*)d_in[21];
  const float* r_k = (const float*)d_in[22];
  const float* Wr  = (const float*)d_in[23];
  const float* Wk  = (const float*)d_in[24];
  const float* Wv  = (const float*)d_in[25];
  const float* Wo  = (const float*)d_in[26];
  const float* lnw = (const float*)d_in[27];
  const float* lnb = (const float*)d_in[28];
  float* outp = (float*)d_out;
  float* ws = (float*)d_ws;

  // workspace layout (floats)
  float* xk  = ws + 0;         // 4*512*512
  float* xv  = ws + 1048576;
  float* kgP = ws + 2097152;   // k raw, packed [b][h][tg][c][4]
  float* vpP = ws + 3145728;   // v_pre, packed
  float* svP = ws + 4194304;   // sigmoid lerp factor, packed
  float* kkP = ws + 5242880;   // normalized kk, packed
  float* Pw  = ws + 6291456;   // 4*512*32
  float* Pa  = ws + 6356992;
  float* Qw  = ws + 6422528;   // 32*32
  float* Qa  = ws + 6423552;
  float* HV  = ws + 6424576;   // 4*512*32
  float* rr  = ws + 7473152;   // 32*512
  float* gr  = ws + 7489536;
  float* xo  = ws + 7505920;
  float* wP  = ws + 7522304;   // 32*512*512 decay, packed [bq][h][tg][c][4]
  float* aP  = ws + 15910912;  // a_sig, packed
  float* xrw = ws + 32688128;  // 32*512
  float* ghw = ws + 32704512;  // 32*96

  k_ps<<<1056, 256, 0, stream>>>(q, kv, x_r, x_w, x_a, x_g, w1, a1, g1,
                                 Qw, Qa, ghw, xrw, x_k, x_v, xk, xv);
  k_rgmm<<<864, 256, 0, stream>>>(xrw, ghw, Wr, g2, rr, gr,
                                  xk, Wk, kgP, xv, Wv, vpP, kv,
                                  x_w, x_a, w1, a1, v1, Pw, Pa, HV);
  k_swa<<<NB*TG + BQ*TG, 512, 0, stream>>>(HV, v2, v0, k_k, kgP, svP, kkP,
                                           Pw, Pa, Qw, Qa, w2, a2, w0, a0,
                                           wP, aP);
  k_scan<<<BQ*HH, 64, 0, stream>>>(wP, aP, kgP, kkP, vpP, svP, vf, rr, gr,
                                   r_k, k_a, lnw, lnb, xo, outp + BQ*CC);
  k_out<<<dim3(8, 32), 256, 0, stream>>>(xo, Wo, outp);
}

// Round 14
// 330.368 us; speedup vs baseline: 1.1697x; 1.1697x over previous
//
#include <hip/hip_runtime.h>
#include <cstdint>

// Problem constants
#define TT 512   // KVLEN
#define CC 512   // C
#define HH 8     // heads
#define NN 64    // head dim
#define BQ 32    // BATCH*QLEN
#define NB 4     // BATCH
#define TG 128   // TT/4 packed groups

__device__ __forceinline__ float sigm(float x){ return 1.f/(1.f+__expf(-x)); }

__device__ __forceinline__ float wsum(float x){
  #pragma unroll
  for (int o=32;o;o>>=1) x += __shfl_xor(x, o, 64);
  return x;
}

// ---------------------------------------------------------------------------
// Batched wave64 row-sum, VALU-only: DPP row_ror tree + permlane16/32 swap.
// ---------------------------------------------------------------------------
template<int NR>
__device__ __forceinline__ void rowsum64_batch(float* x){
  #pragma unroll
  for (int i=0;i<NR;i++)
    x[i] += __int_as_float(__builtin_amdgcn_mov_dpp(__float_as_int(x[i]), 0x121, 0xf, 0xf, true));
  #pragma unroll
  for (int i=0;i<NR;i++)
    x[i] += __int_as_float(__builtin_amdgcn_mov_dpp(__float_as_int(x[i]), 0x122, 0xf, 0xf, true));
  #pragma unroll
  for (int i=0;i<NR;i++)
    x[i] += __int_as_float(__builtin_amdgcn_mov_dpp(__float_as_int(x[i]), 0x124, 0xf, 0xf, true));
  #pragma unroll
  for (int i=0;i<NR;i++)
    x[i] += __int_as_float(__builtin_amdgcn_mov_dpp(__float_as_int(x[i]), 0x128, 0xf, 0xf, true));
  float y[NR];
  #pragma unroll
  for (int i=0;i<NR;i++) asm("v_mov_b32 %0, %1" : "=v"(y[i]) : "v"(x[i]));
  #pragma unroll
  for (int i=0;i<NR;i++) asm("v_permlane16_swap_b32 %0, %1" : "+v"(x[i]), "+v"(y[i]));
  #pragma unroll
  for (int i=0;i<NR;i++) x[i] += y[i];
  #pragma unroll
  for (int i=0;i<NR;i++) asm("v_mov_b32 %0, %1" : "=v"(y[i]) : "v"(x[i]));
  #pragma unroll
  for (int i=0;i<NR;i++) asm("v_permlane32_swap_b32 %0, %1" : "+v"(x[i]), "+v"(y[i]));
  #pragma unroll
  for (int i=0;i<NR;i++) x[i] += y[i];
}

// ---------------------------------------------------------------------------
// k_ps: FUSED k_prep + k_shift (kept from R13 — union LDS is only 6KB).
// Blocks 0..31: prep (per-bq small dots -> Qw/Qa/ghw/xrw).
// Blocks 32..1055: token-shift mix (no LDS).
// ---------------------------------------------------------------------------
__global__ __launch_bounds__(256) void k_ps(
  const float* __restrict__ q, const float* __restrict__ kv,
  const float* __restrict__ x_r, const float* __restrict__ x_w,
  const float* __restrict__ x_a, const float* __restrict__ x_g,
  const float* __restrict__ w1, const float* __restrict__ a1,
  const float* __restrict__ g1,
  float* __restrict__ Qw, float* __restrict__ Qa,
  float* __restrict__ ghw, float* __restrict__ xrw,
  const float* __restrict__ x_k, const float* __restrict__ x_v,
  float* __restrict__ xk, float* __restrict__ xv)
{
  int bid = blockIdx.x;
  int tid = threadIdx.x;
  if (bid < 32){
    // ----- prep part -----
    int bq = bid, b = bq >> 3;
    int wave = tid >> 6, lane = tid & 63;
    __shared__ float qxw[CC], qxa[CC], sxg[CC];
    for (int c = tid; c < CC; c += 256){
      float qv = q[bq*CC + c];
      float kl = kv[((size_t)b*TT + (TT-1))*CC + c];
      xrw[bq*CC + c] = kl + (qv - kl)*x_r[c];
      sxg[c] = kl + (qv - kl)*x_g[c];
      qxw[c] = qv*x_w[c];
      qxa[c] = qv*x_a[c];
    }
    __syncthreads();
    for (int dot = wave; dot < 160; dot += 4){
      const float* buf; const float* W; int ld, dd;
      if (dot < 32)      { buf = qxw; W = w1; ld = 32; dd = dot; }
      else if (dot < 64) { buf = qxa; W = a1; ld = 32; dd = dot-32; }
      else               { buf = sxg; W = g1; ld = 96; dd = dot-64; }
      float s = 0.f;
      #pragma unroll
      for (int m = 0; m < 8; m++){
        int c = m*64 + lane;
        s = fmaf(buf[c], W[c*ld + dd], s);
      }
      s = wsum(s);
      if (lane == 0){
        if (dot < 32)      Qw[bq*32 + dd] = s;
        else if (dot < 64) Qa[bq*32 + dd] = s;
        else               ghw[bq*96 + dd] = sigm(s);
      }
    }
  } else {
    // ----- shift part -----
    int g = (bid - 32)*256 + tid;              // float4 index, [0, 262144)
    int bt = g >> 7, t = bt & (TT-1), c4 = g & 127;
    const float4* kv4 = (const float4*)kv;
    float4 cur = kv4[g];
    float4 sh  = t ? kv4[g-128] : make_float4(0.f,0.f,0.f,0.f);
    float4 kc  = ((const float4*)x_k)[c4];
    float4 vc  = ((const float4*)x_v)[c4];
    float4 ok, ov;
    ok.x = cur.x + (sh.x-cur.x)*kc.x; ov.x = cur.x + (sh.x-cur.x)*vc.x;
    ok.y = cur.y + (sh.y-cur.y)*kc.y; ov.y = cur.y + (sh.y-cur.y)*vc.y;
    ok.z = cur.z + (sh.z-cur.z)*kc.z; ov.z = cur.z + (sh.z-cur.z)*vc.z;
    ok.w = cur.w + (sh.w-cur.w)*kc.w; ov.w = cur.w + (sh.w-cur.w)*vc.w;
    ((float4*)xk)[g] = ok;
    ((float4*)xv)[g] = ov;
  }
}

// ---------------------------------------------------------------------------
// k_rg: rrow[bq,co] = xr[bq,:]@Wr[:,co], grow[bq,co] = gh[bq,:]@g2[:,co]
// (standalone again — R13's 3-way merge unioned LDS to 34KB and broke
// bank-conflict-free padding: 1.57M conflicts, occupancy halved.)
// ---------------------------------------------------------------------------
__global__ __launch_bounds__(256) void k_rg(
  const float* __restrict__ xrw, const float* __restrict__ ghw,
  const float* __restrict__ Wr, const float* __restrict__ g2,
  float* __restrict__ rrow, float* __restrict__ grow)
{
  int bq = blockIdx.y; int co0 = blockIdx.x*64;
  int tid = threadIdx.x, tx = tid & 63, ty = tid >> 6;
  __shared__ float sxr[CC];
  __shared__ float sgh[96];
  __shared__ float red[4][64];
  sxr[tid]     = xrw[bq*CC + tid];
  sxr[tid+256] = xrw[bq*CC + tid + 256];
  if (tid < 96) sgh[tid] = ghw[bq*96 + tid];
  __syncthreads();
  float p = 0.f;
  for (int i = 0; i < 128; i++){
    int c = ty*128 + i;
    p = fmaf(sxr[c], Wr[(size_t)c*CC + co0 + tx], p);
  }
  red[ty][tx] = p;
  float pg = 0.f;
  for (int d = ty*24; d < ty*24 + 24; d++)
    pg = fmaf(sgh[d], g2[(size_t)d*CC + co0 + tx], pg);
  __syncthreads();
  if (ty == 0)
    rrow[bq*CC + co0 + tx] = (red[0][tx]+red[1][tx])+(red[2][tx]+red[3][tx]);
  __syncthreads();
  red[ty][tx] = pg;
  __syncthreads();
  if (ty == 0)
    grow[bq*CC + co0 + tx] = (red[0][tx]+red[1][tx])+(red[2][tx]+red[3][tx]);
}

// ---------------------------------------------------------------------------
// k_mm: FUSED gemm2 + k_pgemm (R12-proven: both branches SHARE the same
// As/Bs/scl declarations -> LDS 18.9KB, no union blowup, no conflicts).
// Blocks 0..95: the three [2048x512]@[512x32] products.
// Blocks 96..607: two [2048x512]@[512x512], packed stores.
// ---------------------------------------------------------------------------
__global__ __launch_bounds__(256) void k_mm(
  const float* __restrict__ xk, const float* __restrict__ Wk,
  float* __restrict__ kgP,
  const float* __restrict__ xv, const float* __restrict__ Wv,
  float* __restrict__ vpP,
  const float* __restrict__ kv,
  const float* __restrict__ x_w, const float* __restrict__ x_a,
  const float* __restrict__ w1, const float* __restrict__ a1,
  const float* __restrict__ v1,
  float* __restrict__ Pw, float* __restrict__ Pa, float* __restrict__ HV)
{
  __shared__ float As[32][68];
  __shared__ float Bs[32][64];
  __shared__ float scl[CC];
  int bid = blockIdx.x;
  int tid = threadIdx.x;

  if (bid < 96){
    // ----- pgemm part -----
    int mat = bid / 32;
    int r0 = (bid % 32) * 64;
    const float* A = (mat == 2) ? xv : kv;
    const float* B = (mat == 0) ? w1 : (mat == 1) ? a1 : v1;
    float* O       = (mat == 0) ? Pw : (mat == 1) ? Pa : HV;
    for (int c = tid; c < CC; c += 256)
      scl[c] = (mat == 0) ? (1.f - x_w[c]) : (mat == 1) ? (1.f - x_a[c]) : 1.f;
    __syncthreads();
    int tx = tid & 31, ty = tid >> 5;
    float acc[8];
    #pragma unroll
    for (int i = 0; i < 8; i++) acc[i] = 0.f;
    for (int k0 = 0; k0 < 512; k0 += 32){
      #pragma unroll
      for (int p = 0; p < 8; p++){
        int e = tid + p*256;
        int kk2 = e & 31, r = e >> 5;
        As[kk2][r] = A[(size_t)(r0+r)*512 + k0 + kk2] * scl[k0 + kk2];
      }
      #pragma unroll
      for (int p = 0; p < 4; p++){
        int e = tid + p*256;
        int n = e & 31, kk2 = e >> 5;
        Bs[kk2][n] = B[(size_t)(k0+kk2)*32 + n];
      }
      __syncthreads();
      #pragma unroll
      for (int kk2 = 0; kk2 < 32; kk2++){
        float bb = Bs[kk2][tx];
        #pragma unroll
        for (int i = 0; i < 8; i++)
          acc[i] = fmaf(As[kk2][ty*8 + i], bb, acc[i]);
      }
      __syncthreads();
    }
    #pragma unroll
    for (int i = 0; i < 8; i++)
      O[(size_t)(r0 + ty*8 + i)*32 + tx] = acc[i];
  } else {
    // ----- gemm part -----
    int gb = bid - 96;
    int z = gb >> 8; int tile = gb & 255;
    const float* A = z ? xv : xk;
    const float* W = z ? Wv : Wk;
    int tx = tid & 15, ty = tid >> 4;
    int m0 = (tile >> 3)*64, n0 = (tile & 7)*64;
    float acc[4][4];
    #pragma unroll
    for (int i=0;i<4;i++)
      #pragma unroll
      for (int j=0;j<4;j++) acc[i][j]=0.f;

    for (int k0 = 0; k0 < 512; k0 += 32){
      #pragma unroll
      for (int i = 0; i < 8; i++){
        int e = tid + i*256;
        int kk = e & 31, m = e >> 5;
        As[kk][m] = A[(size_t)(m0+m)*512 + k0 + kk];
      }
      #pragma unroll
      for (int i = 0; i < 8; i++){
        int e = tid + i*256;
        int n = e & 63, kk = e >> 6;
        Bs[kk][n] = W[(size_t)(k0+kk)*512 + n0 + n];
      }
      __syncthreads();
      #pragma unroll
      for (int kk = 0; kk < 32; kk++){
        float a4[4], b4[4];
        #pragma unroll
        for (int i=0;i<4;i++) a4[i] = As[kk][ty*4+i];
        #pragma unroll
        for (int j=0;j<4;j++) b4[j] = Bs[kk][tx*4+j];
        #pragma unroll
        for (int i=0;i<4;i++)
          #pragma unroll
          for (int j=0;j<4;j++) acc[i][j] += a4[i]*b4[j];
      }
      __syncthreads();
    }
    // packed store: rows m..m+3 are 4 consecutive t (u=0..3)
    int m = m0 + ty*4;
    int b = m >> 9, t = m & (TT-1), tg = t >> 2;
    int h = n0 >> 6;
    float* dstB = z ? vpP : kgP;
    float4* dst = (float4*)dstB + ((size_t)(b*HH + h)*TG + tg)*64 + tx*4;
    #pragma unroll
    for (int j=0;j<4;j++)
      dst[j] = make_float4(acc[0][j],acc[1][j],acc[2][j],acc[3][j]);
  }
}

// ---------------------------------------------------------------------------
// k_swa: FUSED k_svn + k_wa (R12); both 512-thr, mutually independent.
// Blocks 0..511: svn (kk-normalize + sv, packed).
// Blocks 512..4607: wa (decay w + a_sig, packed).
// ---------------------------------------------------------------------------
__global__ __launch_bounds__(512) void k_swa(
  const float* __restrict__ HV, const float* __restrict__ v2,
  const float* __restrict__ v0, const float* __restrict__ k_k,
  const float* __restrict__ kgP,
  float* __restrict__ svP, float* __restrict__ kkP,
  const float* __restrict__ Pw, const float* __restrict__ Pa,
  const float* __restrict__ Qw, const float* __restrict__ Qa,
  const float* __restrict__ w2, const float* __restrict__ a2,
  const float* __restrict__ w0, const float* __restrict__ a0,
  float* __restrict__ wP, float* __restrict__ aP)
{
  int bid = blockIdx.x;
  int tid = threadIdx.x;
  if (bid < NB*TG){
    // ----- svn part -----
    int b = bid >> 7, tg = bid & (TG-1);
    __shared__ float hv[4][32];
    if (tid < 128){
      int u = tid >> 5, d = tid & 31;
      hv[u][d] = HV[((size_t)(b*TT + tg*4 + u))*32 + d];
    }
    __syncthreads();
    int c = tid, h = c >> 6, cc0 = c & 63;
    size_t o = ((size_t)(b*HH + h)*TG + tg)*64 + cc0;
    float4 kg4 = ((const float4*)kgP)[o];
    float kkc = k_k[c];
    float q0 = kg4.x*kkc, q1 = kg4.y*kkc, q2 = kg4.z*kkc, q3 = kg4.w*kkc;
    float ss[4] = {q0*q0, q1*q1, q2*q2, q3*q3};
    rowsum64_batch<4>(ss);            // per-wave = per-head sum
    float4 kkq;
    kkq.x = q0 / fmaxf(sqrtf(ss[0]), 1e-12f);
    kkq.y = q1 / fmaxf(sqrtf(ss[1]), 1e-12f);
    kkq.z = q2 / fmaxf(sqrtf(ss[2]), 1e-12f);
    kkq.w = q3 / fmaxf(sqrtf(ss[3]), 1e-12f);
    ((float4*)kkP)[o] = kkq;
    float v0c = v0[c];
    float s0 = v0c, s1 = v0c, s2 = v0c, s3 = v0c;
    #pragma unroll
    for (int d = 0; d < 32; d++){
      float vc = v2[d*CC + c];
      s0 = fmaf(hv[0][d], vc, s0);
      s1 = fmaf(hv[1][d], vc, s1);
      s2 = fmaf(hv[2][d], vc, s2);
      s3 = fmaf(hv[3][d], vc, s3);
    }
    ((float4*)svP)[o] = make_float4(sigm(s0), sigm(s1), sigm(s2), sigm(s3));
  } else {
    // ----- wa part -----
    int blk = bid - NB*TG;             // bq*TG + tg
    int bq = blk >> 7, tg = blk & (TG-1), t0 = tg*4, b = bq >> 3;
    __shared__ float sth[4][32], sal[4][32];
    if (tid < 256){
      int g = (tid >> 5) & 3, d = tid & 31;
      int pidx = ((b << 9) | (t0 + g))*32 + d;
      if (tid < 128) sth[g][d] = tanhf(Pw[pidx] + Qw[bq*32 + d]);
      else           sal[g][d] = Pa[pidx] + Qa[bq*32 + d];
    }
    __syncthreads();
    int c = tid, h = c >> 6, cc0 = c & 63;
    float wreg[32], areg[32];
    #pragma unroll
    for (int d = 0; d < 32; d++){ wreg[d] = w2[d*CC + c]; areg[d] = a2[d*CC + c]; }
    float w0c = w0[c], a0c = a0[c];
    float w4a[4], a4a[4];
    #pragma unroll
    for (int g = 0; g < 4; g++){
      float wa = 0.f, aa = 0.f;
      #pragma unroll
      for (int d = 0; d < 32; d++){
        wa = fmaf(sth[g][d], wreg[d], wa);
        aa = fmaf(sal[g][d], areg[d], aa);
      }
      w4a[g] = __expf(-0.60653066f * sigm(w0c + wa));
      a4a[g] = sigm(a0c + aa);
    }
    size_t o = ((size_t)(bq*HH + h)*TG + tg)*64 + cc0;
    ((float4*)wP)[o] = make_float4(w4a[0],w4a[1],w4a[2],w4a[3]);
    ((float4*)aP)[o] = make_float4(a4a[0],a4a[1],a4a[2],a4a[3]);
  }
}

// ---------------------------------------------------------------------------
// K3: BACKWARD vector scan — R11 structure (~63-71us measured): R5 geometry,
// vf-passthrough stores youngest per iteration, k/b in-flight.
//   out += v_s (k_s . g_s);  g_{s-1} = w_s*g_s - kk_s (b_s . g_s)
//   k = kg*(1+(a-1)k_a),  b = kk*a.
// ---------------------------------------------------------------------------
#define SCAN_STEP(wc,ac,gc,nc,pc,sc,vfc) do{ \
  float vj = fmaf((vfc)-(pc), (sc), (pc)); \
  float kc = (gc)*fmaf((ac)-1.f, kac, 1.f); \
  float bc = (nc)*(ac); \
  float rr[2]; rr[0]=kc*g; rr[1]=bc*g; \
  rowsum64_batch<2>(rr); \
  out = fmaf(rr[0], vj, out); \
  g = fmaf((wc), g, -((nc)*rr[1])); }while(0)

__global__ __launch_bounds__(64, 1) void k_scan(
  const float* __restrict__ wP, const float* __restrict__ aP,
  const float* __restrict__ kgP, const float* __restrict__ kkP,
  const float* __restrict__ vpP, const float* __restrict__ svP,
  const float* __restrict__ vfirst,
  const float* __restrict__ rrow, const float* __restrict__ grow,
  const float* __restrict__ r_k, const float* __restrict__ k_a,
  const float* __restrict__ ln_w, const float* __restrict__ ln_b,
  float* __restrict__ xo, float* __restrict__ vf_out)
{
  int blk = blockIdx.x; int bq = blk >> 3, h = blk & 7, b = bq >> 3;
  int lane = threadIdx.x & 63;

  // per-(bq,h)/(b,h) packed bases: TG*64 float4s each
  const float4* wp4 = (const float4*)wP  + ((size_t)(bq*HH + h))*TG*64 + lane;
  const float4* ap4 = (const float4*)aP  + ((size_t)(bq*HH + h))*TG*64 + lane;
  const float4* gp4 = (const float4*)kgP + ((size_t)(b*HH + h))*TG*64 + lane;
  const float4* np4 = (const float4*)kkP + ((size_t)(b*HH + h))*TG*64 + lane;
  const float4* pp4 = (const float4*)vpP + ((size_t)(b*HH + h))*TG*64 + lane;
  const float4* sp4 = (const float4*)svP + ((size_t)(b*HH + h))*TG*64 + lane;
  const float*  pvf = vfirst + (size_t)bq*TT*CC + h*NN + lane;
  float*        pvo = vf_out + (size_t)bq*TT*CC + h*NN + lane;

  float kac = k_a[h*NN + lane];
  float g   = rrow[(size_t)bq*CC + h*NN + lane];   // g_{T-1} = r
  float out = 0.f;

  constexpr int PD = 4;                // prefetch depth, in groups of 4 steps
  float4 fw[PD], fa[PD], fg[PD], fn[PD], fp[PD], fs[PD];
  float fv0[PD], fv1[PD], fv2[PD], fv3[PD];
  #pragma unroll
  for (int d = 0; d < PD; ++d){
    int gg = TG-1 - d; int go = gg*64;
    fw[d]=wp4[go]; fa[d]=ap4[go]; fg[d]=gp4[go]; fn[d]=np4[go];
    fp[d]=pp4[go]; fs[d]=sp4[go];
    const float* pv = pvf + (size_t)(4*gg)*CC;
    fv0[d]=pv[0]; fv1[d]=pv[CC]; fv2[d]=pv[2*CC]; fv3[d]=pv[3*CC];
  }

  #pragma unroll 1
  for (int gb = 0; gb < TG; gb += PD){
    #pragma unroll
    for (int sl = 0; sl < PD; ++sl){
      int gi = TG-1 - (gb + sl);       // current group (descending)
      // snapshot slot
      float4 w4=fw[sl], a4=fa[sl], g4=fg[sl], n4=fn[sl], p4=fp[sl], s4=fs[sl];
      float v3=fv3[sl], v2_=fv2[sl], v1_=fv1[sl], v0_=fv0[sl];
      // prefetch group gi-PD into slot sl (clamped; dup loads harmless)
      int gp = gi - PD; gp = gp < 0 ? 0 : gp; int go = gp*64;
      fw[sl]=wp4[go]; fa[sl]=ap4[go]; fg[sl]=gp4[go]; fn[sl]=np4[go];
      fp[sl]=pp4[go]; fs[sl]=sp4[go];
      { const float* pv = pvf + (size_t)(4*gp)*CC;
        fv0[sl]=pv[0]; fv1[sl]=pv[CC]; fv2[sl]=pv[2*CC]; fv3[sl]=pv[3*CC]; }
      // v_first passthrough: issued AFTER the prefetch loads so the stores
      // are the youngest vmem ops — load-consume vmcnt waits no longer
      // require store retirement (R10 regression mechanism).
      {
        float* po = pvo + (size_t)(4*gi)*CC;
        po[0] = v0_; po[CC] = v1_; po[2*CC] = v2_; po[3*CC] = v3;
      }
      __builtin_amdgcn_sched_barrier(0);   // pin loads/stores in this iteration
      // 4 steps, s = 4*gi+3 .. 4*gi+0
      SCAN_STEP(w4.w,a4.w,g4.w,n4.w,p4.w,s4.w,v3);
      SCAN_STEP(w4.z,a4.z,g4.z,n4.z,p4.z,s4.z,v2_);
      SCAN_STEP(w4.y,a4.y,g4.y,n4.y,p4.y,s4.y,v1_);
      SCAN_STEP(w4.x,a4.x,g4.x,n4.x,p4.x,s4.x,v0_);
    }
  }

  // epilogue: groupnorm over head + rk*v term + gate (per-lane channel)
  {
    float mean = wsum(out) * (1.f/NN);
    float dv = out - mean;
    float var = wsum(dv*dv) * (1.f/NN);
    float yn = dv * rsqrtf(var + 6.4e-4f);   // GN_EPS = 1e-5*64
    int c = h*NN + lane;
    float y2 = yn * ln_w[c] + ln_b[c];
    int goT = (TG-1)*64;
    float kgT = gp4[goT].w, aT = ap4[goT].w;
    float kl  = kgT * fmaf(aT - 1.f, kac, 1.f);   // k_final at t = T-1
    float rl  = rrow[(size_t)bq*CC + c];
    float rk  = wsum(rl*kl*r_k[c]);
    float vp_ = pp4[goT].w, sv_ = sp4[goT].w;
    float vf_ = pvf[(size_t)(TT-1)*CC];
    float v_i = fmaf(vf_ - vp_, sv_, vp_);   // v_{T-1}
    float res = (y2 + rk*v_i) * grow[(size_t)bq*CC + c];
    xo[bq*CC + c] = res;
  }
}

// ---------------------------------------------------------------------------
// K4: out[bq,co] = xo[bq,:] @ Wo[:,co]
// ---------------------------------------------------------------------------
__global__ __launch_bounds__(256) void k_out(
  const float* __restrict__ xo, const float* __restrict__ Wo,
  float* __restrict__ outp)
{
  int bq = blockIdx.y; int co0 = blockIdx.x*64;
  int tid = threadIdx.x, tx = tid & 63, ty = tid >> 6;
  __shared__ float row[CC];
  __shared__ float red[4][64];
  row[tid]     = xo[bq*CC + tid];
  row[tid+256] = xo[bq*CC + tid + 256];
  __syncthreads();
  float p = 0.f;
  for (int i = 0; i < 128; i++){
    int c = ty*128 + i;
    p = fmaf(row[c], Wo[(size_t)c*CC + co0 + tx], p);
  }
  red[ty][tx] = p;
  __syncthreads();
  if (ty == 0)
    outp[bq*CC + co0 + tx] = (red[0][tx]+red[1][tx])+(red[2][tx]+red[3][tx]);
}

// ---------------------------------------------------------------------------
extern "C" void kernel_launch(void* const* d_in, const int* in_sizes, int n_in,
                              void* d_out, int out_size, void* d_ws, size_t ws_size,
                              hipStream_t stream)
{
  const float* q   = (const float*)d_in[0];
  const float* kv  = (const float*)d_in[1];
  const float* vf  = (const float*)d_in[2];
  const float* x_r = (const float*)d_in[3];
  const float* x_w = (const float*)d_in[4];
  const float* x_k = (const float*)d_in[5];
  const float* x_v = (const float*)d_in[6];
  const float* x_a = (const float*)d_in[7];
  const float* x_g = (const float*)d_in[8];
  const float* w0  = (const float*)d_in[9];
  const float* w1  = (const float*)d_in[10];
  const float* w2  = (const float*)d_in[11];
  const float* a0  = (const float*)d_in[12];
  const float* a1  = (const float*)d_in[13];
  const float* a2  = (const float*)d_in[14];
  const float* v0  = (const float*)d_in[15];
  const float* v1  = (const float*)d_in[16];
  const float* v2  = (const float*)d_in[17];
  const float* g1  = (const float*)d_in[18];
  const float* g2  = (const float*)d_in[19];
  const float* k_k = (const float*)d_in[20];
  const float* k_a = (const float*)d_in[21];
  const float* r_k = (const float*)d_in[22];
  const float* Wr  = (const float*)d_in[23];
  const float* Wk  = (const float*)d_in[24];
  const float* Wv  = (const float*)d_in[25];
  const float* Wo  = (const float*)d_in[26];
  const float* lnw = (const float*)d_in[27];
  const float* lnb = (const float*)d_in[28];
  float* outp = (float*)d_out;
  float* ws = (float*)d_ws;

  // workspace layout (floats)
  float* xk  = ws + 0;         // 4*512*512
  float* xv  = ws + 1048576;
  float* kgP = ws + 2097152;   // k raw, packed [b][h][tg][c][4]
  float* vpP = ws + 3145728;   // v_pre, packed
  float* svP = ws + 4194304;   // sigmoid lerp factor, packed
  float* kkP = ws + 5242880;   // normalized kk, packed
  float* Pw  = ws + 6291456;   // 4*512*32
  float* Pa  = ws + 6356992;
  float* Qw  = ws + 6422528;   // 32*32
  float* Qa  = ws + 6423552;
  float* HV  = ws + 6424576;   // 4*512*32
  float* rr  = ws + 7473152;   // 32*512
  float* gr  = ws + 7489536;
  float* xo  = ws + 7505920;
  float* wP  = ws + 7522304;   // 32*512*512 decay, packed [bq][h][tg][c][4]
  float* aP  = ws + 15910912;  // a_sig, packed
  float* xrw = ws + 32688128;  // 32*512
  float* ghw = ws + 32704512;  // 32*96

  k_ps<<<1056, 256, 0, stream>>>(q, kv, x_r, x_w, x_a, x_g, w1, a1, g1,
                                 Qw, Qa, ghw, xrw, x_k, x_v, xk, xv);
  k_rg<<<dim3(8, 32), 256, 0, stream>>>(xrw, ghw, Wr, g2, rr, gr);
  k_mm<<<608, 256, 0, stream>>>(xk, Wk, kgP, xv, Wv, vpP, kv,
                                x_w, x_a, w1, a1, v1, Pw, Pa, HV);
  k_swa<<<NB*TG + BQ*TG, 512, 0, stream>>>(HV, v2, v0, k_k, kgP, svP, kkP,
                                           Pw, Pa, Qw, Qa, w2, a2, w0, a0,
                                           wP, aP);
  k_scan<<<BQ*HH, 64, 0, stream>>>(wP, aP, kgP, kkP, vpP, svP, vf, rr, gr,
                                   r_k, k_a, lnw, lnb, xo, outp + BQ*CC);
  k_out<<<dim3(8, 32), 256, 0, stream>>>(xo, Wo, outp);
}